// Round 3
// baseline (41453.784 us; speedup 1.0000x reference)
//
#include <hip/hip_runtime.h>
#include <hip/hip_fp16.h>
#include <math.h>

// LSTM_11089605558768: T=16384 sequential steps, H=512, IN=32, OUT=1.
// Persistent scan, 32 worker wgs x 512 threads.
//
// R9 (base structure = R8; R8 FALSIFIED the 256-thread register budget:
// VGPR 88 < 136 -> weight pin broke, weights re-streamed (FETCH +33MB,
// WRITE 2x spill/write-through) -> 34.4ms. R6's 144-VGPR fit was a
// knife-edge the remap tipped over.)
// R9 fix: 512 threads -> wreg[68]/thread. 68+overhead ~= 100 VGPR at
// 2 waves/SIMD (budget 256): the pin cannot break. Also halves the
// matvec leg (17 ds_read_b128 + 68 FMA) and adds 4 more waves of
// poll latency hiding. Polling is R6-proven verbatim (tid<128 blind
// vmcnt(0) polls, contiguous tid*4 staging = 0 conflicts). One
// barrier/step, parity-double-buffered buf (validated in R8).
//
// lane map (per wave, 8 waves): l = gate*16 + hi*8 + kq
//   gate 0..3 (i,f,g,o), hi 0..1 (h element w*2+hi), kq 0..7 (k-chunk of 68)
//   k-reduce: 3 shfl_xor over kq; gate gather: 4 shfl at base = l&15.
//   publish lanes: gate==0 && kq==0 (l=0,8), 2 per wave = 16 per block.

#define T_STEPS 16384
#define IN_DIM  32
#define H_DIM   512
#define SLOTS   32
#define H_SLICE 16      // H_DIM / SLOTS
#define KTOT    544     // H_DIM + IN_DIM
#define CH      68      // KTOT / 8 (per kq lane)

typedef unsigned int uint32x4 __attribute__((ext_vector_type(4)));

__device__ __forceinline__ float fast_sigmoid(float v) {
  return 1.0f / (1.0f + __expf(-v));
}
__device__ __forceinline__ float fast_tanh(float v) {
  return 2.0f / (1.0f + __expf(-2.0f * v)) - 1.0f;  // 2*sigmoid(2x)-1
}

// --- packet I/O (always LLC-coherent: sc0 sc1) -----------------------------
__device__ __forceinline__ void store_pkt(unsigned int* p, unsigned int v) {
  asm volatile("global_store_dword %0, %1, off sc0 sc1"
               :: "v"(p), "v"(v) : "memory");
}
__device__ __forceinline__ uint32x4 load_pkt4(const unsigned int* p) {
  uint32x4 r;
  asm volatile("global_load_dwordx4 %0, %1, off sc0 sc1\n\ts_waitcnt vmcnt(0)"
               : "=&v"(r) : "v"(p) : "memory");
  return r;
}
__device__ __forceinline__ float pkt_to_f(unsigned int v) {
  return __half2float(__ushort_as_half((unsigned short)(v & 0xFFFFu)));
}

__launch_bounds__(512, 1)
__global__ void lstm_scan_kernel(
    const float* __restrict__ x,     // [T, 32]
    const float* __restrict__ Wih,   // [2048, 32]
    const float* __restrict__ Whh,   // [2048, 512]
    const float* __restrict__ bih,   // [2048]
    const float* __restrict__ bhh,   // [2048]
    const float* __restrict__ Wlin,  // [512]
    const float* __restrict__ blin,  // [1]
    float* __restrict__ out,         // [1]
    unsigned int* pub)               // [2][512] 4B packets (d_ws)
{
  const int slot = blockIdx.x;       // 0..31
  const int tid  = threadIdx.x;      // 0..511
  const int w    = tid >> 6;         // wave 0..7 -> owns h elements w*2, w*2+1
  const int l    = tid & 63;

  const int gate = l >> 4;
  const int hi   = (l >> 3) & 1;
  const int kq   = l & 7;

  // parity-double-buffered staging: [parity][0,512)=h(t), [512,544)=x_t
  __shared__ __align__(16) float buf[2][KTOT];
  __shared__ float red[256];          // final projection only

  const int R = gate * H_DIM + slot * H_SLICE + w * 2 + hi;  // global gate row

  // Persistent weight slice -> registers, pinned with opaque asm identity.
  float wreg[CH];
  #pragma unroll
  for (int j = 0; j < CH; ++j) {
    const int k = kq * CH + j;
    wreg[j] = (k < H_DIM) ? Whh[R * H_DIM + k]
                          : Wih[R * IN_DIM + (k - H_DIM)];
  }
  #pragma unroll
  for (int j = 0; j < CH; ++j)
    asm volatile("v_mov_b32 %0, %0" : "+v"(wreg[j]));

  const float bias = bih[R] + bhh[R];
  float c = 0.0f;  // cell state for h element slot*16+w*2+hi (replicated x32)

  // Polling assignment (R6-proven): tid<128 polls packets [4*tid, 4*tid+4);
  // own-slot group skipped (publishers provide it in fp32).
  const bool poller = (tid < 128) && ((tid >> 2) != slot);
  const bool xthr   = (tid < IN_DIM);

  if (tid < H_SLICE) buf[0][slot * H_SLICE + tid] = 0.0f;  // h(0) own slice

  for (int t = 0; t < T_STEPS; ++t) {
    // x_t load overlaps the poll (independent; consumed after poll resolves)
    float xv = xthr ? x[t * IN_DIM + tid] : 0.0f;

    // ---- gather h(t): blind poll, 4 self-validating packets per thread ----
    if (poller) {
      const unsigned int* p = pub + (t & 1) * H_DIM + tid * 4;
      const unsigned int tg = (unsigned int)t & 0xFFFFu;
      uint32x4 r;
      for (;;) {
        r = load_pkt4(p);
        if ((r.x >> 16) == tg && (r.y >> 16) == tg &&
            (r.z >> 16) == tg && (r.w >> 16) == tg) break;
      }
      float4 hv4;
      hv4.x = pkt_to_f(r.x);
      hv4.y = pkt_to_f(r.y);
      hv4.z = pkt_to_f(r.z);
      hv4.w = pkt_to_f(r.w);
      *(float4*)(&buf[t & 1][tid * 4]) = hv4;  // contiguous: 0 bank conflicts
    }
    if (xthr) buf[t & 1][H_DIM + tid] = xv;
    __syncthreads();  // barrier B: h(t) + x_t staged (the only per-step barrier)

    // ---- matvec: lane covers row (gate,hi), k in [kq*68, kq*68+68) ----
    // float4 bases kq*272B: bank quads 4*kq -> 8 addrs cover 32 banks
    // disjointly; same-kq lanes broadcast. Conflict-free.
    const float4* hv = (const float4*)(&buf[t & 1][kq * CH]);
    float a0 = 0.f, a1 = 0.f, a2 = 0.f, a3 = 0.f;
    #pragma unroll
    for (int q = 0; q < CH / 4; ++q) {
      const float4 h4 = hv[q];
      a0 = fmaf(wreg[4 * q + 0], h4.x, a0);
      a1 = fmaf(wreg[4 * q + 1], h4.y, a1);
      a2 = fmaf(wreg[4 * q + 2], h4.z, a2);
      a3 = fmaf(wreg[4 * q + 3], h4.w, a3);
    }
    float s = (a0 + a1) + (a2 + a3);
    s += __shfl_xor(s, 1, 64);   // reduce over kq (8-lane groups)
    s += __shfl_xor(s, 2, 64);
    s += __shfl_xor(s, 4, 64);
    const float g = s + bias;
    const float act = (gate == 2) ? fast_tanh(g) : fast_sigmoid(g);

    // gather i,f,g,o for this lane's hi (act replicated across kq)
    const int base = l & 15;     // hi*8 + kq
    const float ig = __shfl(act, base,      64);
    const float fg = __shfl(act, base + 16, 64);
    const float gt = __shfl(act, base + 32, 64);
    const float og = __shfl(act, base + 48, 64);
    c = fg * c + ig * gt;
    const float h = og * fast_tanh(c);

    // ---- publish: lanes (gate==0, kq==0), 2 per wave, all waves parallel ----
    if (gate == 0 && kq == 0) {
      const int hidx = slot * H_SLICE + w * 2 + hi;
      buf[(t + 1) & 1][hidx] = h;  // own-slice fp32 shortcut for next step
      const unsigned int pkt =
          (((unsigned int)(t + 1) & 0xFFFFu) << 16) |
          (unsigned int)__half_as_ushort(__float2half_rn(h));
      store_pkt(pub + ((t + 1) & 1) * H_DIM + hidx, pkt);
    }
    // Parity hazards: parity-(t+1) writers (publish fp32 + next poll staging)
    // are separated from parity-(t+1) readers of step t-1 by barrier B(t);
    // parity-(t&1) rewrites at t+2 are separated from matvec-t reads by
    // barrier B(t+1). Single barrier per step suffices (validated R8).
  }

  // ---- slot 0: final projection out = h(T) . Wlin + blin ----
  if (slot != 0) return;
  if (poller) {  // gather h(T) (parity T&1 == 0); own slice already fp32
    const unsigned int* p = pub + (T_STEPS & 1) * H_DIM + tid * 4;
    const unsigned int tg = (unsigned int)T_STEPS & 0xFFFFu;
    uint32x4 r;
    for (;;) {
      r = load_pkt4(p);
      if ((r.x >> 16) == tg && (r.y >> 16) == tg &&
          (r.z >> 16) == tg && (r.w >> 16) == tg) break;
    }
    float4 hv4;
    hv4.x = pkt_to_f(r.x);
    hv4.y = pkt_to_f(r.y);
    hv4.z = pkt_to_f(r.z);
    hv4.w = pkt_to_f(r.w);
    *(float4*)(&buf[0][tid * 4]) = hv4;
  }
  __syncthreads();
  if (tid < 256)
    red[tid] = buf[0][2 * tid] * Wlin[2 * tid] +
               buf[0][2 * tid + 1] * Wlin[2 * tid + 1];
  __syncthreads();
  if (w == 0) {
    float s2 = red[l] + red[64 + l] + red[128 + l] + red[192 + l];
    #pragma unroll
    for (int off = 32; off > 0; off >>= 1) s2 += __shfl_down(s2, off, 64);
    if (l == 0) out[0] = s2 + blin[0];
  }
}

extern "C" void kernel_launch(void* const* d_in, const int* in_sizes, int n_in,
                              void* d_out, int out_size, void* d_ws, size_t ws_size,
                              hipStream_t stream) {
  const float* x    = (const float*)d_in[0];
  const float* Wih  = (const float*)d_in[1];
  const float* Whh  = (const float*)d_in[2];
  const float* bih  = (const float*)d_in[3];
  const float* bhh  = (const float*)d_in[4];
  const float* Wlin = (const float*)d_in[5];
  const float* blin = (const float*)d_in[6];
  float* out = (float*)d_out;

  unsigned int* pub = (unsigned int*)d_ws;  // [2][512] u32 = 4096 B

  // d_ws re-poisoned before every timed call; zeroed pub encodes
  // (tag=0, h=0) == the initial hidden state h(0).
  hipMemsetAsync(d_ws, 0, 4096, stream);
  hipLaunchKernelGGL(lstm_scan_kernel, dim3(SLOTS), dim3(512), 0, stream,
                     x, Wih, Whh, bih, bhh, Wlin, blin, out, pub);
}